// Round 1
// baseline (1173.831 us; speedup 1.0000x reference)
//
#include <hip/hip_runtime.h>

// RegionFeatureLearner: 16 region LSTMs (H=100) over T=2..6 steps, batch 32768,
// + 1-step backward LSTM. Forward recurrence via fp16 MFMA 16x16x32 in the
// "transposed" orientation G^T = W' @ [h|x|1]^T with gate-interleaved rows
// (N' = 4*j + gate) so each lane's 4 accumulator regs are the i,f,g,o gates of
// one (batch m, hidden j) -> gating + cell state fully in registers.

typedef _Float16 f16;
typedef _Float16 half8 __attribute__((ext_vector_type(8)));
typedef float floatx4 __attribute__((ext_vector_type(4)));

#define FEAT_STRIDE 310   // 62*5 floats per batch item
#define AST 136           // A_lds row stride in halves (128 + 8 pad -> 272 B, even bank spread)
#define OST 104           // out-stage row stride in floats (16B-aligned rows)

__constant__ int c_pos[16][6] = {
 {3,0,1,2,4,0},{7,8,9,10,11,0},{5,6,0,0,0,0},{13,12,0,0,0,0},
 {14,15,23,24,32,33},{22,21,31,30,40,39},{16,17,18,19,20,0},{25,26,27,28,29,0},
 {34,35,36,37,38,0},{41,42,0,0,0,0},{49,48,0,0,0,0},{43,44,45,46,47,0},
 {50,51,57,0,0,0},{56,55,61,0,0,0},{52,53,54,0,0,0},{58,59,60,0,0,0}};
__constant__ int c_len[16] = {5,5,2,2,6,6,5,5,5,2,2,5,3,3,3,3};

__device__ __forceinline__ float sigf(float x) {
  return __builtin_amdgcn_rcpf(1.f + __builtin_amdgcn_exp2f(-1.44269504088896f * x));
}
__device__ __forceinline__ float tanhf_fast(float x) {
  // tanh(x) = 1 - 2/(exp(2x)+1)
  return 1.f - 2.f * __builtin_amdgcn_rcpf(1.f + __builtin_amdgcn_exp2f(2.88539008177793f * x));
}

// ---------------------------------------------------------------------------
// Prep: build W'[r][N'=4j+g][k] fp16, k: [0,100)=Whh row, [100,105)=Wih row,
// 105 = b_ih+b_hh, [106,128)=0.  Original gate row = g*100 + j (i,f,g,o chunks).
// ---------------------------------------------------------------------------
__global__ __launch_bounds__(256) void prep_kernel(
    const float* __restrict__ w_ih, const float* __restrict__ w_hh,
    const float* __restrict__ b_ih, const float* __restrict__ b_hh,
    f16* __restrict__ wp)
{
  int id = blockIdx.x * 256 + threadIdx.x;
  if (id >= 16 * 400 * 128) return;
  int k = id & 127;
  int rowN = (id >> 7) % 400;
  int r = (id >> 7) / 400;
  int j = rowN >> 2, g = rowN & 3;
  int orig = (r * 2 + 0) * 400 + g * 100 + j;   // forward direction (dir=0)
  float v;
  if (k < 100)       v = w_hh[orig * 100 + k];
  else if (k < 105)  v = w_ih[orig * 5 + (k - 100)];
  else if (k == 105) v = b_ih[orig] + b_hh[orig];
  else               v = 0.f;
  wp[id] = (f16)v;
}

// ---------------------------------------------------------------------------
// Forward: block = (region r, 32 batch rows). 320 threads = 5 waves, each wave
// owns 5 N'-tiles (25 tiles x 16 rows = 400 gate rows). W' frags in VGPRs.
// A buffer in LDS: [m][k] halves, k in [0,128): h(0..99) x(100..104) 1(105) 0s.
// ---------------------------------------------------------------------------
__global__ __launch_bounds__(320, 3) void fwd_kernel(
    const float* __restrict__ feat, const f16* __restrict__ wp,
    float* __restrict__ out)
{
  __shared__ __align__(16) float smem[32 * OST];   // 13312 B; overlaid as halves for A
  f16* Alds = (f16*)smem;

  const int bx = blockIdx.x;
  const int r  = bx >> 10;               // 1024 m-blocks per region
  const int n0 = (bx & 1023) << 5;       // 32 batch rows per block
  const int tid  = threadIdx.x;
  const int wave = tid >> 6;
  const int lane = tid & 63;
  const int quad = lane >> 4;
  const int l15  = lane & 15;
  const int T = c_len[r];

  // ---- load W' fragments (persist in VGPRs): 5 tiles x 4 kfrags x 8 halves
  half8 wf[5][4];
  {
    const f16* wr = wp + (size_t)r * 400 * 128;
    #pragma unroll
    for (int tn = 0; tn < 5; ++tn) {
      int row = 16 * (5 * wave + tn) + l15;
      #pragma unroll
      for (int kf = 0; kf < 4; ++kf)
        wf[tn][kf] = *(const half8*)(wr + row * 128 + 32 * kf + 8 * quad);
    }
  }

  // ---- init A buffer: h=0, x slots 0 (written below), bias slot (k=105)=1.0
  for (int i = tid; i < 32 * 64; i += 320) {
    int m = i >> 6, kw = i & 63;                      // kw = word index (2 halves)
    ((unsigned int*)smem)[m * (AST / 2) + kw] = (kw == 52) ? 0x3C000000u : 0u;
  }

  // ---- preload all steps' x (threads 0..159: m = tid&31, slot s = tid>>5)
  float xv[6];
  const int xm = tid & 31, xs = tid >> 5;
  if (tid < 160) {
    const float* fb = feat + (size_t)(n0 + xm) * FEAT_STRIDE + xs;
    #pragma unroll
    for (int tt = 0; tt < 6; ++tt)
      if (tt < T) xv[tt] = fb[c_pos[r][tt] * 5];
  }
  __syncthreads();
  if (tid < 160) Alds[xm * AST + 100 + xs] = (f16)xv[0];
  __syncthreads();

  float creg[2][5];
  #pragma unroll
  for (int mt = 0; mt < 2; ++mt)
    #pragma unroll
    for (int tn = 0; tn < 5; ++tn) creg[mt][tn] = 0.f;

  for (int t = 0; t < T; ++t) {
    float hreg[2][5];
    #pragma unroll
    for (int mt = 0; mt < 2; ++mt) {
      // B-operand frags: [h|x|1] rows, 8 consecutive k at fixed m
      half8 bf[4];
      #pragma unroll
      for (int kf = 0; kf < 4; ++kf)
        bf[kf] = *(const half8*)(Alds + (16 * mt + l15) * AST + 32 * kf + 8 * quad);
      #pragma unroll
      for (int tn = 0; tn < 5; ++tn) {
        floatx4 acc = {0.f, 0.f, 0.f, 0.f};
        #pragma unroll
        for (int kf = 0; kf < 4; ++kf)
          acc = __builtin_amdgcn_mfma_f32_16x16x32_f16(wf[tn][kf], bf[kf], acc, 0, 0, 0);
        // lane holds gates i,f,g,o of (m = n0+16*mt+l15, j = 4*(5*wave+tn)+quad)
        float ig = sigf(acc[0]);
        float fg = sigf(acc[1]);
        float gg = tanhf_fast(acc[2]);
        float og = sigf(acc[3]);
        float cn = fg * creg[mt][tn] + ig * gg;
        creg[mt][tn] = cn;
        hreg[mt][tn] = og * tanhf_fast(cn);
      }
    }
    __syncthreads();   // all waves done reading A before overwriting h/x slots
    if (t + 1 < T) {
      #pragma unroll
      for (int mt = 0; mt < 2; ++mt)
        #pragma unroll
        for (int tn = 0; tn < 5; ++tn) {
          int j = 4 * (5 * wave + tn) + quad;
          Alds[(16 * mt + l15) * AST + j] = (f16)hreg[mt][tn];
        }
      if (tid < 160) Alds[xm * AST + 100 + xs] = (f16)xv[t + 1];
    } else {
      // last step: stage h fp32 for coalesced output
      #pragma unroll
      for (int mt = 0; mt < 2; ++mt)
        #pragma unroll
        for (int tn = 0; tn < 5; ++tn) {
          int j = 4 * (5 * wave + tn) + quad;
          smem[(16 * mt + l15) * OST + j] = hreg[mt][tn];
        }
    }
    __syncthreads();
  }

  // ---- coalesced output: out[n][r][0:100], 25 float4 per row
  #pragma unroll
  for (int it = 0; it < 3; ++it) {
    int idx = tid + it * 320;
    if (idx < 800) {
      int m = idx / 25, ch = idx - m * 25;
      floatx4 v = *(const floatx4*)(smem + m * OST + ch * 4);
      *(floatx4*)(out + (size_t)(n0 + m) * 3200 + r * 200 + ch * 4) = v;
    }
  }
}

// ---------------------------------------------------------------------------
// Backward: single step with h0=c0=0 => g = x_last @ Wih_b^T + bias; f unused.
// Block = (region, 128 batch rows); weights (i,g,o rows only) staged in LDS.
// ---------------------------------------------------------------------------
__global__ __launch_bounds__(256) void bwd_kernel(
    const float* __restrict__ feat, const float* __restrict__ w_ih,
    const float* __restrict__ b_ih, const float* __restrict__ b_hh,
    float* __restrict__ out)
{
  __shared__ float wg[300 * 7];   // rows: i(0..99) g(100..199) o(200..299); [w0..w4,bias,pad]
  __shared__ float xs[128 * 5];
  const int bx = blockIdx.x;
  const int r  = bx >> 8;          // 256 n-chunks per region
  const int n0 = (bx & 255) << 7;  // 128 rows per block
  const int tid = threadIdx.x;
  const int pos = c_pos[r][c_len[r] - 1];

  for (int i = tid; i < 2100; i += 256) {
    int row = i / 7, c = i - row * 7;
    int q = row / 100, jj = row - q * 100;
    int qq = (q == 0) ? 0 : (q + 1);            // 0->i, 1->g(2), 2->o(3)
    int orig = (r * 2 + 1) * 400 + qq * 100 + jj;  // backward direction (dir=1)
    float v = 0.f;
    if (c < 5)       v = w_ih[orig * 5 + c];
    else if (c == 5) v = b_ih[orig] + b_hh[orig];
    wg[i] = v;
  }
  for (int i = tid; i < 640; i += 256) {
    int nl = i / 5, s = i - nl * 5;
    xs[i] = feat[(size_t)(n0 + nl) * FEAT_STRIDE + pos * 5 + s];
  }
  __syncthreads();

  for (int idx = tid; idx < 12800; idx += 256) {
    int nl = idx / 100, jj = idx - nl * 100;
    const float* xp = xs + nl * 5;
    float x0 = xp[0], x1 = xp[1], x2 = xp[2], x3 = xp[3], x4 = xp[4];
    const float* wi = wg + jj * 7;
    const float* wc = wg + (100 + jj) * 7;
    const float* wo = wg + (200 + jj) * 7;
    float gi = wi[5] + wi[0]*x0 + wi[1]*x1 + wi[2]*x2 + wi[3]*x3 + wi[4]*x4;
    float gc = wc[5] + wc[0]*x0 + wc[1]*x1 + wc[2]*x2 + wc[3]*x3 + wc[4]*x4;
    float go = wo[5] + wo[0]*x0 + wo[1]*x1 + wo[2]*x2 + wo[3]*x3 + wo[4]*x4;
    float c = sigf(gi) * tanhf_fast(gc);
    float h = sigf(go) * tanhf_fast(c);
    out[(size_t)(n0 + nl) * 3200 + r * 200 + 100 + jj] = h;
  }
}

extern "C" void kernel_launch(void* const* d_in, const int* in_sizes, int n_in,
                              void* d_out, int out_size, void* d_ws, size_t ws_size,
                              hipStream_t stream) {
  const float* feat = (const float*)d_in[0];
  const float* w_ih = (const float*)d_in[1];
  const float* w_hh = (const float*)d_in[2];
  const float* b_ih = (const float*)d_in[3];
  const float* b_hh = (const float*)d_in[4];
  float* out = (float*)d_out;
  f16* wp = (f16*)d_ws;   // 16*400*128*2 = 1.64 MB

  prep_kernel<<<3200, 256, 0, stream>>>(w_ih, w_hh, b_ih, b_hh, wp);
  fwd_kernel<<<16384, 320, 0, stream>>>(feat, wp, out);
  bwd_kernel<<<4096, 256, 0, stream>>>(feat, w_ih, b_ih, b_hh, out);
}